// Round 3
// baseline (318.724 us; speedup 1.0000x reference)
//
#include <hip/hip_runtime.h>
#include <math.h>

#define WH     256
#define NDEPTH 8
#define NBATCH 1024
#define NB     8            // batch elements per block (register reuse)
#define PLANE  (WH * WH)    // 65536
#define TP     65           // LDS transpose tile pitch (floats): 2-way banks max

// ---------------------------------------------------------------------------
// Transpose all 4 arrays [d][w][h] -> ws [arr][d][h][w].
// 512 blocks x 256 threads; 64x64 tile; float4 global reads AND writes.
// bid = arr(2b) | d(3b) | ht(2b) | wt(2b)
// ---------------------------------------------------------------------------
__global__ __launch_bounds__(256) void transpose_all_k(const float* __restrict__ M1,
                                                       const float* __restrict__ B1,
                                                       const float* __restrict__ M2,
                                                       const float* __restrict__ B2,
                                                       float* __restrict__ ws) {
    __shared__ float tile[64 * TP];
    const int bid = blockIdx.x;
    const int arr = bid >> 7;
    const int d   = (bid >> 4) & 7;
    const int ht  = (bid >> 2) & 3;
    const int wt  = bid & 3;

    const float* src = (arr == 0) ? M1 : (arr == 1) ? B1 : (arr == 2) ? M2 : B2;
    const float* s = src + d * PLANE;
    float*       o = ws + ((size_t)arr * NDEPTH + d) * PLANE;

    const int t   = threadIdx.x;
    const int q16 = t >> 4;      // 0..15
    const int r16 = t & 15;      // 0..15

    // read: lane owns float4 along h (contiguous); 16 lanes cover one w-row seg
#pragma unroll
    for (int p = 0; p < 4; ++p) {
        const int wrow = q16 + p * 16;
        const float4 v = *(const float4*)(s + (wt * 64 + wrow) * WH + ht * 64 + r16 * 4);
        tile[wrow * TP + r16 * 4 + 0] = v.x;
        tile[wrow * TP + r16 * 4 + 1] = v.y;
        tile[wrow * TP + r16 * 4 + 2] = v.z;
        tile[wrow * TP + r16 * 4 + 3] = v.w;
    }
    __syncthreads();
    // write: lane owns float4 along w (contiguous in dst)
#pragma unroll
    for (int p = 0; p < 4; ++p) {
        const int hrow = q16 + p * 16;
        float4 v;
        v.x = tile[(r16 * 4 + 0) * TP + hrow];
        v.y = tile[(r16 * 4 + 1) * TP + hrow];
        v.z = tile[(r16 * 4 + 2) * TP + hrow];
        v.w = tile[(r16 * 4 + 3) * TP + hrow];
        *(float4*)(o + (ht * 64 + hrow) * WH + wt * 64 + r16 * 4) = v;
    }
}

// ---------------------------------------------------------------------------
// Main kernel. 256 blocks x 512 threads (8 waves -> 2 waves/SIMD).
// XCD pinning: branch 0 -> XCDs 0..3, branch 1 -> 4..7 (4 MiB set fits L2).
// Wave ws owns h in [ws*32, ws*32+32); lane owns w = lane*4..lane*4+3 (float4).
// Double-buffered 4-h chunks; last chunk of depth d prefetches depth d+1.
// ---------------------------------------------------------------------------
__global__ __launch_bounds__(512) void prop_k(const float4* __restrict__ MT1,
                                              const float4* __restrict__ BT1,
                                              const float4* __restrict__ MT2,
                                              const float4* __restrict__ BT2,
                                              const float* __restrict__ val,
                                              float* __restrict__ out) {
    const int bid   = blockIdx.x;
    const int g     = bid >> 3;
    const int x     = bid & 7;
    const int br    = x >> 2;
    const int bg    = g * 4 + (x & 3);      // 0..127
    const int t     = threadIdx.x;
    const int wave  = t >> 6;               // 0..7: h-chunk owner
    const int lane  = t & 63;
    const int hbase = wave * 32;

    const float4* __restrict__ M = br ? MT2 : MT1;
    const float4* __restrict__ B = br ? BT2 : BT1;

    float q[NB];
#pragma unroll
    for (int nb = 0; nb < NB; ++nb) q[nb] = val[bg * NB + nb];  // block-uniform

    __shared__ float part[8][NB][WH];   // 64 KiB
    __shared__ float qs[NB];

    float4 m[2][4], b[2][4];
    {   // preload chunk 0 of depth 0
        const float4* Mp = M + hbase * 64 + lane;
        const float4* Bp = B + hbase * 64 + lane;
#pragma unroll
        for (int u = 0; u < 4; ++u) { m[0][u] = Mp[u * 64]; b[0][u] = Bp[u * 64]; }
    }

    for (int d = 0; d < NDEPTH; ++d) {
        float acc[NB][4];
#pragma unroll
        for (int nb = 0; nb < NB; ++nb)
#pragma unroll
            for (int c = 0; c < 4; ++c) acc[nb][c] = -INFINITY;

#pragma unroll
        for (int ch = 0; ch < 8; ++ch) {
            const int cur = ch & 1, nxt = cur ^ 1;
            const int it2 = d * 8 + ch + 1;          // next global chunk index
            if (it2 < NDEPTH * 8) {                   // prefetch (crosses depths)
                const int d2  = it2 >> 3;
                const int ch2 = it2 & 7;
                const float4* Mp = M + d2 * (PLANE / 4) + (hbase + ch2 * 4) * 64 + lane;
                const float4* Bp = B + d2 * (PLANE / 4) + (hbase + ch2 * 4) * 64 + lane;
#pragma unroll
                for (int u = 0; u < 4; ++u) { m[nxt][u] = Mp[u * 64]; b[nxt][u] = Bp[u * 64]; }
            }
            // compute: pair h's so acc update folds to v_max3_f32
#pragma unroll
            for (int u = 0; u < 4; u += 2) {
                const float4 ma = m[cur][u], mb = m[cur][u + 1];
                const float4 ba = b[cur][u], bb = b[cur][u + 1];
#pragma unroll
                for (int nb = 0; nb < NB; ++nb) {
                    const float qv = q[nb];
                    acc[nb][0] = fmaxf(acc[nb][0], fmaxf(fmaf(qv, ma.x, ba.x), fmaf(qv, mb.x, bb.x)));
                    acc[nb][1] = fmaxf(acc[nb][1], fmaxf(fmaf(qv, ma.y, ba.y), fmaf(qv, mb.y, bb.y)));
                    acc[nb][2] = fmaxf(acc[nb][2], fmaxf(fmaf(qv, ma.z, ba.z), fmaf(qv, mb.z, bb.z)));
                    acc[nb][3] = fmaxf(acc[nb][3], fmaxf(fmaf(qv, ma.w, ba.w), fmaf(qv, mb.w, bb.w)));
                }
            }
        }

        // stage per-wave partial maxes: part[wave][nb][w]
#pragma unroll
        for (int nb = 0; nb < NB; ++nb) {
            *(float4*)&part[wave][nb][lane * 4] =
                make_float4(acc[nb][0], acc[nb][1], acc[nb][2], acc[nb][3]);
        }
        __syncthreads();

        // reduce: wave `nbr` handles batch nbr; lane owns 4 w via float4
        {
            const int nbr = t >> 6;    // 0..7 == NB
            float4 v = *(const float4*)&part[0][nbr][lane * 4];
#pragma unroll
            for (int s = 1; s < 8; ++s) {
                const float4 w4 = *(const float4*)&part[s][nbr][lane * 4];
                v.x = fmaxf(v.x, w4.x); v.y = fmaxf(v.y, w4.y);
                v.z = fmaxf(v.z, w4.z); v.w = fmaxf(v.w, w4.w);
            }
            float r = fminf(fminf(v.x, v.y), fminf(v.z, v.w));
#pragma unroll
            for (int off = 32; off > 0; off >>= 1)
                r = fminf(r, __shfl_xor(r, off, 64));
            if (lane == 0) qs[nbr] = r;
        }
        __syncthreads();
#pragma unroll
        for (int nb = 0; nb < NB; ++nb) q[nb] = qs[nb];
        // part[] rewritten next depth only after this barrier -> safe
    }

    if (t < NB) out[br * NBATCH + bg * NB + t] = qs[t];
}

// ---------------------------------------------------------------------------
extern "C" void kernel_launch(void* const* d_in, const int* in_sizes, int n_in,
                              void* d_out, int out_size, void* d_ws, size_t ws_size,
                              hipStream_t stream) {
    const float* val = (const float*)d_in[0];
    const float* M1  = (const float*)d_in[1];
    const float* B1  = (const float*)d_in[2];
    const float* M2  = (const float*)d_in[3];
    const float* B2  = (const float*)d_in[4];
    float* out = (float*)d_out;

    const size_t arr_elems = (size_t)NDEPTH * PLANE;   // 524288 floats per array
    float* ws  = (float*)d_ws;                         // needs 8 MiB (verified R2)
    float* MT1 = ws + 0 * arr_elems;
    float* BT1 = ws + 1 * arr_elems;
    float* MT2 = ws + 2 * arr_elems;
    float* BT2 = ws + 3 * arr_elems;

    transpose_all_k<<<dim3(512), dim3(256), 0, stream>>>(M1, B1, M2, B2, ws);

    prop_k<<<dim3(256), dim3(512), 0, stream>>>((const float4*)MT1, (const float4*)BT1,
                                                (const float4*)MT2, (const float4*)BT2,
                                                val, out);
}